// Round 3
// baseline (181.065 us; speedup 1.0000x reference)
//
#include <hip/hip_runtime.h>

// DynamicMaskHead fused v7 (MI355X / gfx950)
// = v4 (best measured, ~56us imputed) + depth-1 input prefetch (T14 split).
// pack_kernel: mask_feats (4,8,128,128) -> rec (4,16384,8) pixel-major in ws.
// dmh_kernel: grid = n_inst x 8 row-groups (16 logits rows -> 32 out rows).
//   Block: 17x128 logits tile (halo row above, clamped) via 10->8->8->1 MLP
//   (block-uniform scalar weights in SGPRs, pixel feats via 2x dwordx4),
//   parity-split LDS, factor-2 aligned_bilinear closed form, float4 stores.
//   NEW: iteration u+1's inputs (and the tail's input) are loaded into
//   registers BEFORE iteration u's MLP, hiding ~500cy VMEM latency under
//   ~600cy of FMA work. Keep VGPR <= 64 (occupancy cliff).
//
// aligned_bilinear(factor=2): odd Y -> copy logits row (Y-1)/2; even Y ->
// avg rows (Y/2-1, Y/2); Y=0 falls out via clamped halo. Same in X:
// out[4l..4l+3] from logits cols {2l-1, 2l, 2l+1}.

#define HW 16384
#define NP 169

__global__ __launch_bounds__(256)
void pack_kernel(const float* __restrict__ mf, float* __restrict__ rec)
{
    const int g   = blockIdx.x * 256 + threadIdx.x;   // 0..65535
    const int img = g >> 14;
    const int p   = g & 16383;
    const float* fb = mf + (size_t)img * 8 * HW + p;
    float4 a = make_float4(fb[0],      fb[HW],     fb[2 * HW], fb[3 * HW]);
    float4 b = make_float4(fb[4 * HW], fb[5 * HW], fb[6 * HW], fb[7 * HW]);
    float4* o = (float4*)(rec + (size_t)g * 8);
    o[0] = a;
    o[1] = b;
}

__global__ __launch_bounds__(256, 6)
void dmh_kernel(const float* __restrict__ mask_feats,   // (4,8,128,128)
                const float* __restrict__ mask_shift,   // (16384,2)
                const float* __restrict__ shifts,       // (n,2)
                const float* __restrict__ inst_params,  // (n,169)
                const int*   __restrict__ im_inds,      // (n,)
                const int*   __restrict__ fpn_levels,   // (n,)
                const float* __restrict__ rec,          // (4,16384,8) or null
                float*       __restrict__ out,          // (n,1,256,256)
                int use_rec)
{
    __shared__ float lgE[17 * 64];   // even cols
    __shared__ float lgO[17 * 64];   // odd cols

    const int bx   = blockIdx.x;
    const int inst = bx >> 3;
    const int rg   = bx & 7;
    const int tid  = threadIdx.x;
    const int r0   = rg * 16;

    const int img = im_inds[inst];
    const float* __restrict__ wp = inst_params + (size_t)inst * NP;
    const float s0  = shifts[2 * inst];
    const float s1  = shifts[2 * inst + 1];
    const float inv = 1.0f / (float)(64 << fpn_levels[inst]);
    const float* __restrict__ fb = mask_feats + (size_t)img * 8 * HW;
    const float* __restrict__ rb = rec + (size_t)img * 8 * HW;

    // load MLP input for tile pixel p (tile row p>>7, clamped halo)
    auto load_px = [&](int p, float* x) {
        const int t = p >> 7;
        const int c = p & 127;
        const int r = min(max(r0 - 1 + t, 0), 127);
        const int g = r * 128 + c;
        const float2 ms = *(const float2*)(mask_shift + 2 * g);
        x[0] = (s0 - ms.x) * inv;
        x[1] = (s1 - ms.y) * inv;
        if (use_rec) {
            const float4* q = (const float4*)(rb + (size_t)g * 8);
            const float4 a = q[0], b = q[1];
            x[2] = a.x; x[3] = a.y; x[4] = a.z; x[5] = a.w;
            x[6] = b.x; x[7] = b.y; x[8] = b.z; x[9] = b.w;
        } else {
            #pragma unroll
            for (int k = 0; k < 8; ++k) x[2 + k] = fb[k * HW + g];
        }
    };

    auto store_px = [&](int p, float v) {
        const int t = p >> 7;
        const int c = p & 127;
        const int idx = t * 64 + (c >> 1);
        if (c & 1) lgO[idx] = v; else lgE[idx] = v;
    };

    // ---- phase A: software-pipelined pair MLP over 17x128 tile ----
    float cxa[10], cxb[10], nxa[10], nxb[10];
    load_px(tid,       cxa);
    load_px(tid + 256, cxb);

    #pragma unroll
    for (int u = 0; u < 4; ++u) {
        // prefetch next iteration's inputs (tail input at u==3)
        if (u < 3) {
            load_px(tid + 512 * (u + 1),       nxa);
            load_px(tid + 512 * (u + 1) + 256, nxb);
        } else if (tid < 128) {
            load_px(2048 + tid, nxa);
        }

        // pair MLP on current inputs
        float ya[8], yb[8];
        #pragma unroll
        for (int o = 0; o < 8; ++o) {
            const float bia = wp[152 + o];
            float a = bia, b = bia;
            #pragma unroll
            for (int c = 0; c < 10; ++c) {
                const float w = wp[o * 10 + c];
                a = fmaf(w, cxa[c], a);
                b = fmaf(w, cxb[c], b);
            }
            ya[o] = fmaxf(a, 0.f);
            yb[o] = fmaxf(b, 0.f);
        }
        float za[8], zb[8];
        #pragma unroll
        for (int o = 0; o < 8; ++o) {
            const float bia = wp[160 + o];
            float a = bia, b = bia;
            #pragma unroll
            for (int c = 0; c < 8; ++c) {
                const float w = wp[80 + o * 8 + c];
                a = fmaf(w, ya[c], a);
                b = fmaf(w, yb[c], b);
            }
            za[o] = fmaxf(a, 0.f);
            zb[o] = fmaxf(b, 0.f);
        }
        float va = wp[168], vb = va;
        #pragma unroll
        for (int c = 0; c < 8; ++c) {
            const float w = wp[144 + c];
            va = fmaf(w, za[c], va);
            vb = fmaf(w, zb[c], vb);
        }
        store_px(tid + 512 * u,       va);
        store_px(tid + 512 * u + 256, vb);

        // rotate prefetch buffers (renamed away by full unroll)
        #pragma unroll
        for (int k = 0; k < 10; ++k) { cxa[k] = nxa[k]; cxb[k] = nxb[k]; }
    }

    if (tid < 128) {                 // tail px 2048..2175, input prefetched
        float y1[8];
        #pragma unroll
        for (int o = 0; o < 8; ++o) {
            float a = wp[152 + o];
            #pragma unroll
            for (int c = 0; c < 10; ++c) a = fmaf(wp[o * 10 + c], cxa[c], a);
            y1[o] = fmaxf(a, 0.f);
        }
        float y2[8];
        #pragma unroll
        for (int o = 0; o < 8; ++o) {
            float a = wp[160 + o];
            #pragma unroll
            for (int c = 0; c < 8; ++c) a = fmaf(wp[80 + o * 8 + c], y1[c], a);
            y2[o] = fmaxf(a, 0.f);
        }
        float v = wp[168];
        #pragma unroll
        for (int c = 0; c < 8; ++c) v = fmaf(wp[144 + c], y2[c], v);
        store_px(2048 + tid, v);
    }

    __syncthreads();

    // ---- phase B: 32 output rows x 256 cols, float4 stores ----
    float* __restrict__ op =
        out + (size_t)inst * 65536 + (size_t)(2 * r0) * 256;
    const int w = tid >> 6;
    const int l = tid & 63;
    const int parity = w & 1;        // wave-uniform row parity

    #pragma unroll
    for (int j = 0; j < 8; ++j) {
        const int p2 = (w >> 1) + 2 * j;     // 0..15
        const int yl = 2 * p2 + parity;
        float4 res;
        if (parity) {                // odd row: fy=0, logits tile row p2+1
            const float* e = lgE + (p2 + 1) * 64;
            const float* o = lgO + (p2 + 1) * 64;
            const float v0 = e[l];
            const float v1 = o[l];
            const float vm = (l > 0) ? o[l - 1] : v0;
            res = make_float4(0.5f * (vm + v0), v0, 0.5f * (v0 + v1), v1);
        } else {                     // even row: fy=0.5, tile rows p2, p2+1
            const float* eA = lgE + p2 * 64;
            const float* oA = lgO + p2 * 64;
            const float* eB = eA + 64;
            const float* oB = oA + 64;
            const float v0A = eA[l], v1A = oA[l];
            const float v0B = eB[l], v1B = oB[l];
            const float vmA = (l > 0) ? oA[l - 1] : v0A;
            const float vmB = (l > 0) ? oB[l - 1] : v0B;
            res = make_float4(0.25f * (vmA + v0A + vmB + v0B),
                              0.5f  * (v0A + v0B),
                              0.25f * (v0A + v1A + v0B + v1B),
                              0.5f  * (v1A + v1B));
        }
        *(float4*)(op + yl * 256 + 4 * l) = res;
    }
}

extern "C" void kernel_launch(void* const* d_in, const int* in_sizes, int n_in,
                              void* d_out, int out_size, void* d_ws, size_t ws_size,
                              hipStream_t stream) {
    (void)n_in; (void)out_size;
    const float* mask_feats  = (const float*)d_in[0];
    const float* mask_shift  = (const float*)d_in[1];
    const float* shifts      = (const float*)d_in[2];
    const float* inst_params = (const float*)d_in[3];
    const int*   im_inds     = (const int*)d_in[4];
    const int*   fpn_levels  = (const int*)d_in[5];
    float* out = (float*)d_out;
    float* rec = (float*)d_ws;

    const int n_inst = in_sizes[2] / 2;            // shifts is (n,2)
    const size_t rec_bytes = (size_t)4 * HW * 8 * sizeof(float);
    const int use_rec = (ws_size >= rec_bytes) ? 1 : 0;

    if (use_rec)
        pack_kernel<<<dim3(4 * HW / 256), dim3(256), 0, stream>>>(
            mask_feats, rec);

    dmh_kernel<<<dim3(n_inst * 8), dim3(256), 0, stream>>>(
        mask_feats, mask_shift, shifts, inst_params, im_inds, fpn_levels,
        rec, out, use_rec);
}

// Round 4
// 152.242 us; speedup vs baseline: 1.1893x; 1.1893x over previous
//
#include <hip/hip_runtime.h>

// DynamicMaskHead fused v4 (MI355X / gfx950) — restored champion.
// Rounds 1-3 post-mortem: v5 (33-row tile, direct feats) 80.4us, v6 (16-row
// tile + reg halo + lb(256,8)) 85.6us, v7 (v4 + manual prefetch) 84.1us.
// v4 measured <64us (absent from round-0 top-5; imputed ~56us from the
// stable 93-97us harness-fill overhead). Phase-A codegen is fragile:
// every perturbation (tile size, launch bounds, prefetch) regressed.
// DO NOT touch the phase-A loop structure without counters for THIS build.
//
// pack_kernel: mask_feats (4,8,128,128) -> rec (4,16384,8) pixel-major in ws.
// dmh_kernel: grid = n_inst x 8 row-groups (16 logits rows -> 32 out rows).
//   Block: 17x128 logits tile (halo row above, clamped) via 10->8->8->1 MLP
//   (block-uniform scalar weights, pixel feats via 2x dwordx4), parity-split
//   LDS, factor-2 aligned_bilinear closed form, float4 stores.
//
// aligned_bilinear(factor=2): uy=max(Y-1,0); odd Y -> copy logits row
// (Y-1)/2; even Y -> avg rows (Y/2-1, Y/2); Y=0 falls out via clamped halo.
// Same in X: out[4l..4l+3] from logits cols {2l-1, 2l, 2l+1}.

#define HW 16384
#define NP 169

__global__ __launch_bounds__(256)
void pack_kernel(const float* __restrict__ mf, float* __restrict__ rec)
{
    const int g   = blockIdx.x * 256 + threadIdx.x;   // 0..65535
    const int img = g >> 14;
    const int p   = g & 16383;
    const float* fb = mf + (size_t)img * 8 * HW + p;
    float4 a = make_float4(fb[0],      fb[HW],     fb[2 * HW], fb[3 * HW]);
    float4 b = make_float4(fb[4 * HW], fb[5 * HW], fb[6 * HW], fb[7 * HW]);
    float4* o = (float4*)(rec + (size_t)g * 8);
    o[0] = a;
    o[1] = b;
}

__global__ __launch_bounds__(256, 6)
void dmh_kernel(const float* __restrict__ mask_feats,   // (4,8,128,128)
                const float* __restrict__ mask_shift,   // (16384,2)
                const float* __restrict__ shifts,       // (n,2)
                const float* __restrict__ inst_params,  // (n,169)
                const int*   __restrict__ im_inds,      // (n,)
                const int*   __restrict__ fpn_levels,   // (n,)
                const float* __restrict__ rec,          // (4,16384,8) or null
                float*       __restrict__ out,          // (n,1,256,256)
                int use_rec)
{
    __shared__ float lgE[17 * 64];   // even cols
    __shared__ float lgO[17 * 64];   // odd cols

    const int bx   = blockIdx.x;
    const int inst = bx >> 3;
    const int rg   = bx & 7;
    const int tid  = threadIdx.x;
    const int r0   = rg * 16;

    const int img = im_inds[inst];
    const float* __restrict__ wp = inst_params + (size_t)inst * NP;
    const float s0  = shifts[2 * inst];
    const float s1  = shifts[2 * inst + 1];
    const float inv = 1.0f / (float)(64 << fpn_levels[inst]);
    const float* __restrict__ fb = mask_feats + (size_t)img * 8 * HW;
    const float* __restrict__ rb = rec + (size_t)img * 8 * HW;

    // ---- phase A: MLP over 17x128 tile (pixel p -> tile row p>>7) ----
    auto load_px = [&](int p, float* x) {
        const int t = p >> 7;
        const int c = p & 127;
        const int r = min(max(r0 - 1 + t, 0), 127);
        const int g = r * 128 + c;
        const float2 ms = *(const float2*)(mask_shift + 2 * g);
        x[0] = (s0 - ms.x) * inv;
        x[1] = (s1 - ms.y) * inv;
        if (use_rec) {
            const float4* q = (const float4*)(rb + (size_t)g * 8);
            const float4 a = q[0], b = q[1];
            x[2] = a.x; x[3] = a.y; x[4] = a.z; x[5] = a.w;
            x[6] = b.x; x[7] = b.y; x[8] = b.z; x[9] = b.w;
        } else {
            #pragma unroll
            for (int k = 0; k < 8; ++k) x[2 + k] = fb[k * HW + g];
        }
    };

    auto store_px = [&](int p, float v) {
        const int t = p >> 7;
        const int c = p & 127;
        const int idx = t * 64 + (c >> 1);
        if (c & 1) lgO[idx] = v; else lgE[idx] = v;
    };

    // pair-processing: 4 pair-calls cover 2048 px, tail covers 128
    #pragma unroll
    for (int u = 0; u < 4; ++u) {
        const int pA = tid + 512 * u;
        const int pB = pA + 256;
        float xa[10], xb[10];
        load_px(pA, xa);
        load_px(pB, xb);

        float ya[8], yb[8];
        #pragma unroll
        for (int o = 0; o < 8; ++o) {
            const float bia = wp[152 + o];
            float a = bia, b = bia;
            #pragma unroll
            for (int c = 0; c < 10; ++c) {
                const float w = wp[o * 10 + c];
                a = fmaf(w, xa[c], a);
                b = fmaf(w, xb[c], b);
            }
            ya[o] = fmaxf(a, 0.f);
            yb[o] = fmaxf(b, 0.f);
        }
        float za[8], zb[8];
        #pragma unroll
        for (int o = 0; o < 8; ++o) {
            const float bia = wp[160 + o];
            float a = bia, b = bia;
            #pragma unroll
            for (int c = 0; c < 8; ++c) {
                const float w = wp[80 + o * 8 + c];
                a = fmaf(w, ya[c], a);
                b = fmaf(w, yb[c], b);
            }
            za[o] = fmaxf(a, 0.f);
            zb[o] = fmaxf(b, 0.f);
        }
        float va = wp[168], vb = va;
        #pragma unroll
        for (int c = 0; c < 8; ++c) {
            const float w = wp[144 + c];
            va = fmaf(w, za[c], va);
            vb = fmaf(w, zb[c], vb);
        }
        store_px(pA, va);
        store_px(pB, vb);
    }

    if (tid < 128) {                 // tail px 2048..2175, waves 0-1 only
        const int p = 2048 + tid;
        float x[10];
        load_px(p, x);
        float y1[8];
        #pragma unroll
        for (int o = 0; o < 8; ++o) {
            float a = wp[152 + o];
            #pragma unroll
            for (int c = 0; c < 10; ++c) a = fmaf(wp[o * 10 + c], x[c], a);
            y1[o] = fmaxf(a, 0.f);
        }
        float y2[8];
        #pragma unroll
        for (int o = 0; o < 8; ++o) {
            float a = wp[160 + o];
            #pragma unroll
            for (int c = 0; c < 8; ++c) a = fmaf(wp[80 + o * 8 + c], y1[c], a);
            y2[o] = fmaxf(a, 0.f);
        }
        float v = wp[168];
        #pragma unroll
        for (int c = 0; c < 8; ++c) v = fmaf(wp[144 + c], y2[c], v);
        store_px(p, v);
    }

    __syncthreads();

    // ---- phase B: 32 output rows x 256 cols, float4 stores ----
    float* __restrict__ op =
        out + (size_t)inst * 65536 + (size_t)(2 * r0) * 256;
    const int w = tid >> 6;
    const int l = tid & 63;
    const int parity = w & 1;        // wave-uniform row parity

    #pragma unroll
    for (int j = 0; j < 8; ++j) {
        const int p2 = (w >> 1) + 2 * j;     // 0..15
        const int yl = 2 * p2 + parity;
        float4 res;
        if (parity) {                // odd row: fy=0, logits row p2+1
            const float* e = lgE + (p2 + 1) * 64;
            const float* o = lgO + (p2 + 1) * 64;
            const float v0 = e[l];
            const float v1 = o[l];
            const float vm = (l > 0) ? o[l - 1] : v0;
            res = make_float4(0.5f * (vm + v0), v0, 0.5f * (v0 + v1), v1);
        } else {                     // even row: fy=0.5, rows p2, p2+1
            const float* eA = lgE + p2 * 64;
            const float* oA = lgO + p2 * 64;
            const float* eB = eA + 64;
            const float* oB = oA + 64;
            const float v0A = eA[l], v1A = oA[l];
            const float v0B = eB[l], v1B = oB[l];
            const float vmA = (l > 0) ? oA[l - 1] : v0A;
            const float vmB = (l > 0) ? oB[l - 1] : v0B;
            res = make_float4(0.25f * (vmA + v0A + vmB + v0B),
                              0.5f  * (v0A + v0B),
                              0.25f * (v0A + v1A + v0B + v1B),
                              0.5f  * (v1A + v1B));
        }
        *(float4*)(op + yl * 256 + 4 * l) = res;
    }
}

extern "C" void kernel_launch(void* const* d_in, const int* in_sizes, int n_in,
                              void* d_out, int out_size, void* d_ws, size_t ws_size,
                              hipStream_t stream) {
    (void)n_in; (void)out_size;
    const float* mask_feats  = (const float*)d_in[0];
    const float* mask_shift  = (const float*)d_in[1];
    const float* shifts      = (const float*)d_in[2];
    const float* inst_params = (const float*)d_in[3];
    const int*   im_inds     = (const int*)d_in[4];
    const int*   fpn_levels  = (const int*)d_in[5];
    float* out = (float*)d_out;
    float* rec = (float*)d_ws;

    const int n_inst = in_sizes[2] / 2;            // shifts is (n,2)
    const size_t rec_bytes = (size_t)4 * HW * 8 * sizeof(float);
    const int use_rec = (ws_size >= rec_bytes) ? 1 : 0;

    if (use_rec)
        pack_kernel<<<dim3(4 * HW / 256), dim3(256), 0, stream>>>(
            mask_feats, rec);

    dmh_kernel<<<dim3(n_inst * 8), dim3(256), 0, stream>>>(
        mask_feats, mask_shift, shifts, inst_params, im_inds, fpn_levels,
        rec, out, use_rec);
}